// Round 11
// baseline (216.856 us; speedup 1.0000x reference)
//
#include <hip/hip_runtime.h>
#include <hip/hip_fp16.h>
#include <math.h>

// GCN 2-layer (DGL GraphConv norm='both'). SIX regular launches, no memset.
// Fusion vehicles all proven pathological (r7/r8 coop = harness 20x slowdown;
// r9 SW-barrier = 240us/barrier atomic serialization; r10 epilogue-graft into
// K1 = regalloc flip to 56 VGPR -> W1 spill, 66us). So: minimum launches with
// every phase body byte-identical to its proven-fast version.
//   K1 histA_featw1 (round-6 VERBATIM -- regalloc-fragile, do not touch):
//      per-block LDS hists of dst>>8 / src>>8 -> dhist[bin*T+b | M+...];
//      featw1 = fp16(feat @ W1), W1 column in 64 NAMED VGPRs, feat via LDS.
//   K2 scan_bins (2 blocks): per-bin totals by summing dhist rows (613KB, L2)
//      + block scan -> bases + cursors. Replaces 3 scan launches AND memset.
//   K3 partition: block b reserves rb=atomicAdd(cursor[bin], dhist[bin*T+b]),
//      scatters packed (src|dstLow<<17) + src-low bytes in ONE pass.
//      Within-bin chunk order arbitrary -- harmless (sums order-insensitive;
//      validated r0/r10 pass).
//   K4 finalize: dst bins -> in_deg/row_start/csr_src; src bins -> out_deg +
//      featp *= rsqrt(out_deg).
//   K5 agg1: one wave/node, 8 edge-groups x 8 fp16 chunks; relu+b1+.W2 -> s_buf
//   K6 agg2: 16 lanes/node -> sigmoid -> out
// Requires N <= 65536 (src packed into 17 bits, NB <= 256). N=50000 here.

#define BS 256
#define EPB 2048    // edges per hist/partition chunk (8 iters of 256)

// ---- K1: per-block dst+src hists + featw1 (round-6 verbatim) ----
__global__ __launch_bounds__(256, 4)
void histA_featw1_kernel(const int* __restrict__ src, const int* __restrict__ dst,
                         const float* __restrict__ feat, const float* __restrict__ W1,
                         int* __restrict__ dhist,
                         __half* __restrict__ featp,
                         int E, int N, int NB, int T, int M) {
    __shared__ float4 ftile[64 * 16];   // 64 feat rows (16KB)
    __shared__ int histD[256];
    __shared__ int histS[256];
    int tid = threadIdx.x;
    if ((int)blockIdx.x < T) {
        histD[tid] = 0; histS[tid] = 0;
        __syncthreads();
        int base = blockIdx.x * EPB;
        #pragma unroll
        for (int it = 0; it < EPB / BS; it++) {
            int e = base + it * BS + tid;
            if (e < E) {
                atomicAdd(&histD[dst[e] >> 8], 1);
                atomicAdd(&histS[src[e] >> 8], 1);
            }
        }
        __syncthreads();
        if (tid < NB) {
            dhist[tid * T + (int)blockIdx.x] = histD[tid];
            dhist[M + tid * T + (int)blockIdx.x] = histS[tid];
        }
    } else {
        int lane = tid & 63;
        int wave = tid >> 6;
        // W1 column for this lane: 64 named scalars (static -> registers).
        #define WD(i) float wv##i = W1[(i) * 64 + lane];
        WD(0)  WD(1)  WD(2)  WD(3)  WD(4)  WD(5)  WD(6)  WD(7)
        WD(8)  WD(9)  WD(10) WD(11) WD(12) WD(13) WD(14) WD(15)
        WD(16) WD(17) WD(18) WD(19) WD(20) WD(21) WD(22) WD(23)
        WD(24) WD(25) WD(26) WD(27) WD(28) WD(29) WD(30) WD(31)
        WD(32) WD(33) WD(34) WD(35) WD(36) WD(37) WD(38) WD(39)
        WD(40) WD(41) WD(42) WD(43) WD(44) WD(45) WD(46) WD(47)
        WD(48) WD(49) WD(50) WD(51) WD(52) WD(53) WD(54) WD(55)
        WD(56) WD(57) WD(58) WD(59) WD(60) WD(61) WD(62) WD(63)
        #undef WD
        // stage 64 feat rows into LDS (coalesced, 4 float4/thread)
        int rBase = ((int)blockIdx.x - T) * 64;
        const float4* feat4 = (const float4*)feat;
        int maxF4 = N * 16 - 1;
        #pragma unroll
        for (int it = 0; it < 4; it++) {
            int idx = it * BS + tid;
            ftile[idx] = feat4[min(rBase * 16 + idx, maxF4)];
        }
        __syncthreads();
        // 16 rows per wave; per row: 16 b128 broadcast reads + 64 FMA
        #pragma unroll 1
        for (int rr = 0; rr < 16; rr++) {
            int r = wave * 16 + rr;
            const float4* ft = &ftile[r * 16];
            float a0 = 0.0f, a1 = 0.0f, a2 = 0.0f, a3 = 0.0f;
            #define RK(k4, wA, wB, wC, wD_) { float4 f = ft[k4]; \
                a0 = fmaf(f.x, wA, a0); a1 = fmaf(f.y, wB, a1); \
                a2 = fmaf(f.z, wC, a2); a3 = fmaf(f.w, wD_, a3); }
            RK(0,  wv0,  wv1,  wv2,  wv3)  RK(1,  wv4,  wv5,  wv6,  wv7)
            RK(2,  wv8,  wv9,  wv10, wv11) RK(3,  wv12, wv13, wv14, wv15)
            RK(4,  wv16, wv17, wv18, wv19) RK(5,  wv20, wv21, wv22, wv23)
            RK(6,  wv24, wv25, wv26, wv27) RK(7,  wv28, wv29, wv30, wv31)
            RK(8,  wv32, wv33, wv34, wv35) RK(9,  wv36, wv37, wv38, wv39)
            RK(10, wv40, wv41, wv42, wv43) RK(11, wv44, wv45, wv46, wv47)
            RK(12, wv48, wv49, wv50, wv51) RK(13, wv52, wv53, wv54, wv55)
            RK(14, wv56, wv57, wv58, wv59) RK(15, wv60, wv61, wv62, wv63)
            #undef RK
            int rowg = rBase + r;
            if (rowg < N)
                featp[(size_t)rowg * 64 + lane] = __float2half((a0 + a1) + (a2 + a3));
        }
    }
}

// ---- K2: bin totals from dhist rows + scan -> bases/cursors (2 blocks) ----
__global__ void scan_bins_kernel(const int* __restrict__ dhist,
                                 int* __restrict__ binBase, int* __restrict__ cursor,
                                 int NB, int T, int M) {
    __shared__ int s[256];
    int t = threadIdx.x;
    int side = blockIdx.x;              // 0 = dst, 1 = src
    int v = 0;
    if (t < NB) {
        const int* row = dhist + side * M + t * T;   // contiguous T ints
        for (int c = 0; c < T; c++) v += row[c];
    }
    s[t] = v; __syncthreads();
    for (int off = 1; off < 256; off <<= 1) {
        int u = (t >= off) ? s[t - off] : 0; __syncthreads();
        s[t] += u; __syncthreads();
    }
    int* bb  = binBase + side * (NB + 1);
    int* cur = cursor + side * NB;
    if (t < NB) {
        int ex = s[t] - v;
        bb[t] = ex; cur[t] = ex;
        if (t == NB - 1) bb[NB] = s[t];
    }
}

// ---- K3: partition: reserve ranges via cursor atomics, scatter both sides ----
__global__ void partition_kernel(const int* __restrict__ src, const int* __restrict__ dst,
                                 const int* __restrict__ dhist,
                                 int* __restrict__ dstCursor, int* __restrict__ srcCursor,
                                 int* __restrict__ packed, unsigned char* __restrict__ srcPartB,
                                 int E, int NB, int T, int M) {
    __shared__ int darr[256];
    __shared__ int sarr[256];
    int tid = threadIdx.x;
    int b = blockIdx.x;
    int hd = (tid < NB) ? dhist[tid * T + b] : 0;
    int hs = (tid < NB) ? dhist[M + tid * T + b] : 0;
    darr[tid] = (hd > 0) ? atomicAdd(&dstCursor[tid], hd) : 0;
    sarr[tid] = (hs > 0) ? atomicAdd(&srcCursor[tid], hs) : 0;
    __syncthreads();
    int base = b * EPB;
    #pragma unroll
    for (int it = 0; it < EPB / BS; it++) {
        int e = base + it * BS + tid;
        if (e < E) {
            int d = dst[e], s2 = src[e];
            int pos = atomicAdd(&darr[d >> 8], 1);
            packed[pos] = s2 | ((d & 255) << 17);
            int pos2 = atomicAdd(&sarr[s2 >> 8], 1);
            srcPartB[pos2] = (unsigned char)(s2 & 255);
        }
    }
}

// ---- K4: finalize: dst bins -> CSR; src bins -> out_deg + featp rescale ----
__global__ void finalize_kernel(const int* __restrict__ dstBinBase, const int* __restrict__ srcBinBase,
                                const int* __restrict__ packed,
                                const unsigned char* __restrict__ srcPartB,
                                int* __restrict__ csr_src, int* __restrict__ in_deg,
                                int* __restrict__ row_start, int* __restrict__ out_deg,
                                __half* __restrict__ featp,
                                int N, int NB) {
    __shared__ int hist[256];
    __shared__ int sc[256];
    int tid = threadIdx.x;
    int b = blockIdx.x;
    if (b < NB) {
        int lo = dstBinBase[b], hi = dstBinBase[b + 1];
        hist[tid] = 0; __syncthreads();
        for (int i = lo + tid; i < hi; i += BS)
            atomicAdd(&hist[(packed[i] >> 17) & 255], 1);
        __syncthreads();
        int v = hist[tid];
        sc[tid] = v; __syncthreads();
        for (int off = 1; off < 256; off <<= 1) {
            int u = (tid >= off) ? sc[tid - off] : 0; __syncthreads();
            sc[tid] += u; __syncthreads();
        }
        int ex = sc[tid] - v;          // exclusive within bin
        int n = b * 256 + tid;
        if (n < N) { in_deg[n] = v; row_start[n] = lo + ex; }
        sc[tid] = lo + ex;             // becomes the scatter cursor
        __syncthreads();
        for (int i = lo + tid; i < hi; i += BS) {
            int pv = packed[i];
            int pos = atomicAdd(&sc[(pv >> 17) & 255], 1);
            csr_src[pos] = pv & 0x1FFFF;
        }
    } else {
        int sb = b - NB;
        int lo = srcBinBase[sb], hi = srcBinBase[sb + 1];
        hist[tid] = 0; __syncthreads();
        for (int i = lo + tid; i < hi; i += BS)
            atomicAdd(&hist[srcPartB[i]], 1);
        __syncthreads();
        int n = sb * 256 + tid;
        int od = hist[tid];
        if (n < N) out_deg[n] = od;
        float* snorm = (float*)sc;     // reuse LDS
        snorm[tid] = rsqrtf(fmaxf((float)od, 1.0f));
        __syncthreads();
        // pre-scale featp rows of this bin by out_norm (contiguous 32KB block)
        int nodes = min(256, N - sb * 256);
        uint4* fp = (uint4*)(featp + (size_t)sb * 256 * 64);   // 8 uint4 per row
        int total = nodes * 8;
        for (int i = tid; i < total; i += BS) {
            float s = snorm[i >> 3];   // 8 lanes share a node -> LDS broadcast
            uint4 u = fp[i];
            __half2* hh = (__half2*)&u;
            #pragma unroll
            for (int c = 0; c < 4; c++) {
                float2 p = __half22float2(hh[c]);
                p.x *= s; p.y *= s;
                hh[c] = __float22half2_rn(p);
            }
            fp[i] = u;
        }
    }
}

// ---- K5: agg1: one wave/node; 8 edge-groups x 8 chunks; featp pre-scaled ----
__global__ void csr_agg1_kernel(const int* __restrict__ row_start, const int* __restrict__ in_deg,
                                const int* __restrict__ csr_src, const int* __restrict__ out_deg,
                                const __half* __restrict__ featp,
                                const float* __restrict__ b1, const float* __restrict__ W2,
                                float* __restrict__ s_buf, int N) {
    int gid = blockIdx.x * blockDim.x + threadIdx.x;
    int n = gid >> 6;
    if (n >= N) return;
    int lane = threadIdx.x & 63;
    int g = lane >> 3;   // edge slot within batch of 8
    int l = lane & 7;    // feature chunk: features [8l, 8l+8)
    int start = row_start[n];
    int deg = in_deg[n];
    float acc[8] = {0, 0, 0, 0, 0, 0, 0, 0};
    const uint4* fp4 = (const uint4*)featp;
    for (int j = 0; j < deg; j += 16) {
        int e0 = j + g;
        int e1 = j + 8 + g;
        bool p0 = e0 < deg;
        bool p1 = e1 < deg;
        int sn0 = p0 ? csr_src[start + e0] : 0;
        int sn1 = p1 ? csr_src[start + e1] : 0;
        uint4 q0 = {0, 0, 0, 0}, q1 = {0, 0, 0, 0};
        if (p0) q0 = fp4[(size_t)sn0 * 8 + l];
        if (p1) q1 = fp4[(size_t)sn1 * 8 + l];
        const __half2* h0 = (const __half2*)&q0;
        const __half2* h1 = (const __half2*)&q1;
        #pragma unroll
        for (int c = 0; c < 4; c++) {
            float2 f0 = __half22float2(h0[c]);
            float2 f1 = __half22float2(h1[c]);
            acc[2 * c]     += f0.x + f1.x;
            acc[2 * c + 1] += f0.y + f1.y;
        }
    }
    #pragma unroll
    for (int off = 8; off < 64; off <<= 1) {
        #pragma unroll
        for (int c = 0; c < 8; c++)
            acc[c] += __shfl_xor(acc[c], off, 64);
    }
    float inn = rsqrtf(fmaxf((float)deg, 1.0f));
    float v = 0.0f;
    #pragma unroll
    for (int c = 0; c < 8; c++) {
        float h = fmaxf(inn * acc[c] + b1[l * 8 + c], 0.0f);
        v += h * W2[l * 8 + c];
    }
    #pragma unroll
    for (int off = 1; off < 8; off <<= 1)
        v += __shfl_xor(v, off, 64);
    if (lane == 0)
        s_buf[n] = rsqrtf(fmaxf((float)out_deg[n], 1.0f)) * v;
}

// ---- K6: agg2: 16 lanes/node, unroll-2, sigmoid -> out ----
__global__ void csr_agg2_kernel(const int* __restrict__ row_start, const int* __restrict__ in_deg,
                                const int* __restrict__ csr_src,
                                const float* __restrict__ s_buf, const float* __restrict__ b2,
                                float* __restrict__ out, int N) {
    int gid = blockIdx.x * blockDim.x + threadIdx.x;
    int n = gid >> 4;
    if (n >= N) return;
    int sub = gid & 15;
    int start = row_start[n];
    int deg = in_deg[n];
    float a = 0.0f;
    for (int j = sub; j < deg; j += 32) {
        int j1 = j + 16;
        int i0 = csr_src[start + j];
        int i1 = (j1 < deg) ? csr_src[start + j1] : 0;
        float v0 = s_buf[i0];
        float v1 = (j1 < deg) ? s_buf[i1] : 0.0f;
        a += v0 + v1;
    }
    #pragma unroll
    for (int off = 1; off < 16; off <<= 1)
        a += __shfl_xor(a, off, 64);
    if (sub == 0) {
        float x = rsqrtf(fmaxf((float)deg, 1.0f)) * a + b2[0];
        out[n] = 1.0f / (1.0f + expf(-x));
    }
}

extern "C" void kernel_launch(void* const* d_in, const int* in_sizes, int n_in,
                              void* d_out, int out_size, void* d_ws, size_t ws_size,
                              hipStream_t stream) {
    const float* feat = (const float*)d_in[0];
    const float* W1   = (const float*)d_in[1];
    const float* b1   = (const float*)d_in[2];
    const float* W2   = (const float*)d_in[3];
    const float* b2   = (const float*)d_in[4];
    const int* src = (const int*)d_in[5];
    const int* dst = (const int*)d_in[6];
    float* out = (float*)d_out;

    int N  = in_sizes[0] / 64;       // 50000
    int E  = in_sizes[5];            // 800000
    int NB = (N + 255) >> 8;         // 196 bins of 256 nodes
    int T  = (E + EPB - 1) / EPB;    // 391 hist/partition chunks
    int M  = NB * T;                 // per-side flat (bin, chunk) counts

    // workspace: bases/cursors | per-node | dhist | edge arrays | fp16 | f32
    int* wsi = (int*)d_ws;
    int* binBase     = wsi;                          // 2*(NB+1) (written by K2)
    int* cursor      = binBase + 2 * (NB + 1);       // 2*NB     (written by K2)
    int* in_deg      = cursor + 2 * NB;              // N
    int* row_start   = in_deg + N;                   // N
    int* out_deg     = row_start + N;                // N
    int* dhist       = out_deg + N;                  // 2*M (fully overwritten)
    int* packed      = dhist + 2 * M;                // E
    int* csr_src     = packed + E;                   // E
    unsigned char* srcPartB = (unsigned char*)(csr_src + E);      // E bytes
    size_t int_bytes = ((size_t)(4 * NB + 2) + 3 * (size_t)N + 2 * (size_t)M + 2 * (size_t)E) * sizeof(int)
                     + (size_t)E;
    size_t half_off  = (int_bytes + 15) & ~(size_t)15;
    __half* featp = (__half*)((char*)d_ws + half_off);            // 64N fp16
    float* s_buf  = (float*)((char*)d_ws + half_off + (size_t)64 * N * sizeof(__half));

    int* dstBinBase = binBase;
    int* srcBinBase = binBase + (NB + 1);
    int* dstCursor  = cursor;
    int* srcCursor  = cursor + NB;

    histA_featw1_kernel<<<T + (N + 63) / 64, BS, 0, stream>>>(
        src, dst, feat, W1, dhist, featp, E, N, NB, T, M);
    scan_bins_kernel<<<2, BS, 0, stream>>>(dhist, binBase, cursor, NB, T, M);
    partition_kernel<<<T, BS, 0, stream>>>(
        src, dst, dhist, dstCursor, srcCursor, packed, srcPartB, E, NB, T, M);
    finalize_kernel<<<2 * NB, BS, 0, stream>>>(
        dstBinBase, srcBinBase, packed, srcPartB, csr_src, in_deg, row_start,
        out_deg, featp, N, NB);
    csr_agg1_kernel<<<(int)(((size_t)N * 64 + BS - 1) / BS), BS, 0, stream>>>(
        row_start, in_deg, csr_src, out_deg, featp, b1, W2, s_buf, N);
    csr_agg2_kernel<<<(int)(((size_t)N * 16 + BS - 1) / BS), BS, 0, stream>>>(
        row_start, in_deg, csr_src, s_buf, b2, out, N);
}

// Round 12
// 182.002 us; speedup vs baseline: 1.1915x; 1.1915x over previous
//
#include <hip/hip_runtime.h>
#include <hip/hip_fp16.h>
#include <math.h>

// GCN 2-layer (DGL GraphConv norm='both'). SIX regular launches, no memset.
// Fusion vehicles all proven pathological (r7/r8 coop = harness 20x slowdown;
// r9 SW-barrier = 240us/barrier atomic serialization; r10 epilogue-graft into
// K1 = regalloc flip to 56 VGPR -> W1 spill, 66us). Minimum launches with
// every phase body byte-identical to its proven-fast version.
//   K1 histA_featw1 (round-6 VERBATIM -- regalloc-fragile, do not touch):
//      per-block LDS hists of dst>>8 / src>>8 -> dhist[bin*T+b | M+...];
//      featw1 = fp16(feat @ W1), W1 column in 64 NAMED VGPRs, feat via LDS.
//   K2 scan_bins (2 blocks x 1024): WAVE-PARALLEL bin totals -- each of 16
//      waves sums every-16th bin's contiguous 391-int dhist row coalesced
//      across 64 lanes + shfl reduce (r11's 1-thread-per-row serial version
//      was 55us latency-bound at 0.08% occupancy); then 256-thread block
//      scan -> bases + cursors. Replaces 3 scan launches AND memset.
//   K3 partition: block b reserves rb=atomicAdd(cursor[bin], dhist[bin*T+b]),
//      scatters packed (src|dstLow<<17) + src-low bytes in ONE pass.
//      Within-bin chunk order arbitrary -- harmless (sums order-insensitive).
//   K4 finalize: dst bins -> in_deg/row_start/csr_src; src bins -> out_deg +
//      featp *= rsqrt(out_deg).
//   K5 agg1: one wave/node, 8 edge-groups x 8 fp16 chunks; relu+b1+.W2 -> s_buf
//   K6 agg2: 16 lanes/node -> sigmoid -> out
// Requires N <= 65536 (src packed into 17 bits, NB <= 256). N=50000 here.

#define BS 256
#define EPB 2048    // edges per hist/partition chunk (8 iters of 256)

// ---- K1: per-block dst+src hists + featw1 (round-6 verbatim) ----
__global__ __launch_bounds__(256, 4)
void histA_featw1_kernel(const int* __restrict__ src, const int* __restrict__ dst,
                         const float* __restrict__ feat, const float* __restrict__ W1,
                         int* __restrict__ dhist,
                         __half* __restrict__ featp,
                         int E, int N, int NB, int T, int M) {
    __shared__ float4 ftile[64 * 16];   // 64 feat rows (16KB)
    __shared__ int histD[256];
    __shared__ int histS[256];
    int tid = threadIdx.x;
    if ((int)blockIdx.x < T) {
        histD[tid] = 0; histS[tid] = 0;
        __syncthreads();
        int base = blockIdx.x * EPB;
        #pragma unroll
        for (int it = 0; it < EPB / BS; it++) {
            int e = base + it * BS + tid;
            if (e < E) {
                atomicAdd(&histD[dst[e] >> 8], 1);
                atomicAdd(&histS[src[e] >> 8], 1);
            }
        }
        __syncthreads();
        if (tid < NB) {
            dhist[tid * T + (int)blockIdx.x] = histD[tid];
            dhist[M + tid * T + (int)blockIdx.x] = histS[tid];
        }
    } else {
        int lane = tid & 63;
        int wave = tid >> 6;
        // W1 column for this lane: 64 named scalars (static -> registers).
        #define WD(i) float wv##i = W1[(i) * 64 + lane];
        WD(0)  WD(1)  WD(2)  WD(3)  WD(4)  WD(5)  WD(6)  WD(7)
        WD(8)  WD(9)  WD(10) WD(11) WD(12) WD(13) WD(14) WD(15)
        WD(16) WD(17) WD(18) WD(19) WD(20) WD(21) WD(22) WD(23)
        WD(24) WD(25) WD(26) WD(27) WD(28) WD(29) WD(30) WD(31)
        WD(32) WD(33) WD(34) WD(35) WD(36) WD(37) WD(38) WD(39)
        WD(40) WD(41) WD(42) WD(43) WD(44) WD(45) WD(46) WD(47)
        WD(48) WD(49) WD(50) WD(51) WD(52) WD(53) WD(54) WD(55)
        WD(56) WD(57) WD(58) WD(59) WD(60) WD(61) WD(62) WD(63)
        #undef WD
        // stage 64 feat rows into LDS (coalesced, 4 float4/thread)
        int rBase = ((int)blockIdx.x - T) * 64;
        const float4* feat4 = (const float4*)feat;
        int maxF4 = N * 16 - 1;
        #pragma unroll
        for (int it = 0; it < 4; it++) {
            int idx = it * BS + tid;
            ftile[idx] = feat4[min(rBase * 16 + idx, maxF4)];
        }
        __syncthreads();
        // 16 rows per wave; per row: 16 b128 broadcast reads + 64 FMA
        #pragma unroll 1
        for (int rr = 0; rr < 16; rr++) {
            int r = wave * 16 + rr;
            const float4* ft = &ftile[r * 16];
            float a0 = 0.0f, a1 = 0.0f, a2 = 0.0f, a3 = 0.0f;
            #define RK(k4, wA, wB, wC, wD_) { float4 f = ft[k4]; \
                a0 = fmaf(f.x, wA, a0); a1 = fmaf(f.y, wB, a1); \
                a2 = fmaf(f.z, wC, a2); a3 = fmaf(f.w, wD_, a3); }
            RK(0,  wv0,  wv1,  wv2,  wv3)  RK(1,  wv4,  wv5,  wv6,  wv7)
            RK(2,  wv8,  wv9,  wv10, wv11) RK(3,  wv12, wv13, wv14, wv15)
            RK(4,  wv16, wv17, wv18, wv19) RK(5,  wv20, wv21, wv22, wv23)
            RK(6,  wv24, wv25, wv26, wv27) RK(7,  wv28, wv29, wv30, wv31)
            RK(8,  wv32, wv33, wv34, wv35) RK(9,  wv36, wv37, wv38, wv39)
            RK(10, wv40, wv41, wv42, wv43) RK(11, wv44, wv45, wv46, wv47)
            RK(12, wv48, wv49, wv50, wv51) RK(13, wv52, wv53, wv54, wv55)
            RK(14, wv56, wv57, wv58, wv59) RK(15, wv60, wv61, wv62, wv63)
            #undef RK
            int rowg = rBase + r;
            if (rowg < N)
                featp[(size_t)rowg * 64 + lane] = __float2half((a0 + a1) + (a2 + a3));
        }
    }
}

// ---- K2: wave-parallel bin totals + scan -> bases/cursors (2 x 1024) ----
__global__ void scan_bins_kernel(const int* __restrict__ dhist,
                                 int* __restrict__ binBase, int* __restrict__ cursor,
                                 int NB, int T, int M) {
    __shared__ int stot[256];
    __shared__ int s[256];
    int tid = threadIdx.x;
    int side = blockIdx.x;              // 0 = dst, 1 = src
    int wid = tid >> 6, lane = tid & 63;
    // 16 waves; wave w sums bins w, w+16, ... coalesced across 64 lanes
    for (int t = wid; t < NB; t += 16) {
        const int* row = dhist + (size_t)side * M + (size_t)t * T;
        int v = 0;
        for (int c = lane; c < T; c += 64) v += row[c];
        #pragma unroll
        for (int off = 1; off < 64; off <<= 1)
            v += __shfl_xor(v, off, 64);
        if (lane == 0) stot[t] = v;
    }
    __syncthreads();
    int v = (tid < NB) ? stot[tid] : 0;
    if (tid < 256) s[tid] = v;
    __syncthreads();
    for (int off = 1; off < 256; off <<= 1) {
        int u = (tid < 256 && tid >= off) ? s[tid - off] : 0;
        __syncthreads();
        if (tid < 256) s[tid] += u;
        __syncthreads();
    }
    int* bb  = binBase + side * (NB + 1);
    int* cur = cursor + side * NB;
    if (tid < NB) {
        int ex = s[tid] - v;
        bb[tid] = ex; cur[tid] = ex;
        if (tid == NB - 1) bb[NB] = s[tid];
    }
}

// ---- K3: partition: reserve ranges via cursor atomics, scatter both sides ----
__global__ void partition_kernel(const int* __restrict__ src, const int* __restrict__ dst,
                                 const int* __restrict__ dhist,
                                 int* __restrict__ dstCursor, int* __restrict__ srcCursor,
                                 int* __restrict__ packed, unsigned char* __restrict__ srcPartB,
                                 int E, int NB, int T, int M) {
    __shared__ int darr[256];
    __shared__ int sarr[256];
    int tid = threadIdx.x;
    int b = blockIdx.x;
    int hd = (tid < NB) ? dhist[tid * T + b] : 0;
    int hs = (tid < NB) ? dhist[M + tid * T + b] : 0;
    darr[tid] = (hd > 0) ? atomicAdd(&dstCursor[tid], hd) : 0;
    sarr[tid] = (hs > 0) ? atomicAdd(&srcCursor[tid], hs) : 0;
    __syncthreads();
    int base = b * EPB;
    #pragma unroll
    for (int it = 0; it < EPB / BS; it++) {
        int e = base + it * BS + tid;
        if (e < E) {
            int d = dst[e], s2 = src[e];
            int pos = atomicAdd(&darr[d >> 8], 1);
            packed[pos] = s2 | ((d & 255) << 17);
            int pos2 = atomicAdd(&sarr[s2 >> 8], 1);
            srcPartB[pos2] = (unsigned char)(s2 & 255);
        }
    }
}

// ---- K4: finalize: dst bins -> CSR; src bins -> out_deg + featp rescale ----
__global__ void finalize_kernel(const int* __restrict__ dstBinBase, const int* __restrict__ srcBinBase,
                                const int* __restrict__ packed,
                                const unsigned char* __restrict__ srcPartB,
                                int* __restrict__ csr_src, int* __restrict__ in_deg,
                                int* __restrict__ row_start, int* __restrict__ out_deg,
                                __half* __restrict__ featp,
                                int N, int NB) {
    __shared__ int hist[256];
    __shared__ int sc[256];
    int tid = threadIdx.x;
    int b = blockIdx.x;
    if (b < NB) {
        int lo = dstBinBase[b], hi = dstBinBase[b + 1];
        hist[tid] = 0; __syncthreads();
        for (int i = lo + tid; i < hi; i += BS)
            atomicAdd(&hist[(packed[i] >> 17) & 255], 1);
        __syncthreads();
        int v = hist[tid];
        sc[tid] = v; __syncthreads();
        for (int off = 1; off < 256; off <<= 1) {
            int u = (tid >= off) ? sc[tid - off] : 0; __syncthreads();
            sc[tid] += u; __syncthreads();
        }
        int ex = sc[tid] - v;          // exclusive within bin
        int n = b * 256 + tid;
        if (n < N) { in_deg[n] = v; row_start[n] = lo + ex; }
        sc[tid] = lo + ex;             // becomes the scatter cursor
        __syncthreads();
        for (int i = lo + tid; i < hi; i += BS) {
            int pv = packed[i];
            int pos = atomicAdd(&sc[(pv >> 17) & 255], 1);
            csr_src[pos] = pv & 0x1FFFF;
        }
    } else {
        int sb = b - NB;
        int lo = srcBinBase[sb], hi = srcBinBase[sb + 1];
        hist[tid] = 0; __syncthreads();
        for (int i = lo + tid; i < hi; i += BS)
            atomicAdd(&hist[srcPartB[i]], 1);
        __syncthreads();
        int n = sb * 256 + tid;
        int od = hist[tid];
        if (n < N) out_deg[n] = od;
        float* snorm = (float*)sc;     // reuse LDS
        snorm[tid] = rsqrtf(fmaxf((float)od, 1.0f));
        __syncthreads();
        // pre-scale featp rows of this bin by out_norm (contiguous 32KB block)
        int nodes = min(256, N - sb * 256);
        uint4* fp = (uint4*)(featp + (size_t)sb * 256 * 64);   // 8 uint4 per row
        int total = nodes * 8;
        for (int i = tid; i < total; i += BS) {
            float s = snorm[i >> 3];   // 8 lanes share a node -> LDS broadcast
            uint4 u = fp[i];
            __half2* hh = (__half2*)&u;
            #pragma unroll
            for (int c = 0; c < 4; c++) {
                float2 p = __half22float2(hh[c]);
                p.x *= s; p.y *= s;
                hh[c] = __float22half2_rn(p);
            }
            fp[i] = u;
        }
    }
}

// ---- K5: agg1: one wave/node; 8 edge-groups x 8 chunks; featp pre-scaled ----
__global__ void csr_agg1_kernel(const int* __restrict__ row_start, const int* __restrict__ in_deg,
                                const int* __restrict__ csr_src, const int* __restrict__ out_deg,
                                const __half* __restrict__ featp,
                                const float* __restrict__ b1, const float* __restrict__ W2,
                                float* __restrict__ s_buf, int N) {
    int gid = blockIdx.x * blockDim.x + threadIdx.x;
    int n = gid >> 6;
    if (n >= N) return;
    int lane = threadIdx.x & 63;
    int g = lane >> 3;   // edge slot within batch of 8
    int l = lane & 7;    // feature chunk: features [8l, 8l+8)
    int start = row_start[n];
    int deg = in_deg[n];
    float acc[8] = {0, 0, 0, 0, 0, 0, 0, 0};
    const uint4* fp4 = (const uint4*)featp;
    for (int j = 0; j < deg; j += 16) {
        int e0 = j + g;
        int e1 = j + 8 + g;
        bool p0 = e0 < deg;
        bool p1 = e1 < deg;
        int sn0 = p0 ? csr_src[start + e0] : 0;
        int sn1 = p1 ? csr_src[start + e1] : 0;
        uint4 q0 = {0, 0, 0, 0}, q1 = {0, 0, 0, 0};
        if (p0) q0 = fp4[(size_t)sn0 * 8 + l];
        if (p1) q1 = fp4[(size_t)sn1 * 8 + l];
        const __half2* h0 = (const __half2*)&q0;
        const __half2* h1 = (const __half2*)&q1;
        #pragma unroll
        for (int c = 0; c < 4; c++) {
            float2 f0 = __half22float2(h0[c]);
            float2 f1 = __half22float2(h1[c]);
            acc[2 * c]     += f0.x + f1.x;
            acc[2 * c + 1] += f0.y + f1.y;
        }
    }
    #pragma unroll
    for (int off = 8; off < 64; off <<= 1) {
        #pragma unroll
        for (int c = 0; c < 8; c++)
            acc[c] += __shfl_xor(acc[c], off, 64);
    }
    float inn = rsqrtf(fmaxf((float)deg, 1.0f));
    float v = 0.0f;
    #pragma unroll
    for (int c = 0; c < 8; c++) {
        float h = fmaxf(inn * acc[c] + b1[l * 8 + c], 0.0f);
        v += h * W2[l * 8 + c];
    }
    #pragma unroll
    for (int off = 1; off < 8; off <<= 1)
        v += __shfl_xor(v, off, 64);
    if (lane == 0)
        s_buf[n] = rsqrtf(fmaxf((float)out_deg[n], 1.0f)) * v;
}

// ---- K6: agg2: 16 lanes/node, unroll-2, sigmoid -> out ----
__global__ void csr_agg2_kernel(const int* __restrict__ row_start, const int* __restrict__ in_deg,
                                const int* __restrict__ csr_src,
                                const float* __restrict__ s_buf, const float* __restrict__ b2,
                                float* __restrict__ out, int N) {
    int gid = blockIdx.x * blockDim.x + threadIdx.x;
    int n = gid >> 4;
    if (n >= N) return;
    int sub = gid & 15;
    int start = row_start[n];
    int deg = in_deg[n];
    float a = 0.0f;
    for (int j = sub; j < deg; j += 32) {
        int j1 = j + 16;
        int i0 = csr_src[start + j];
        int i1 = (j1 < deg) ? csr_src[start + j1] : 0;
        float v0 = s_buf[i0];
        float v1 = (j1 < deg) ? s_buf[i1] : 0.0f;
        a += v0 + v1;
    }
    #pragma unroll
    for (int off = 1; off < 16; off <<= 1)
        a += __shfl_xor(a, off, 64);
    if (sub == 0) {
        float x = rsqrtf(fmaxf((float)deg, 1.0f)) * a + b2[0];
        out[n] = 1.0f / (1.0f + expf(-x));
    }
}

extern "C" void kernel_launch(void* const* d_in, const int* in_sizes, int n_in,
                              void* d_out, int out_size, void* d_ws, size_t ws_size,
                              hipStream_t stream) {
    const float* feat = (const float*)d_in[0];
    const float* W1   = (const float*)d_in[1];
    const float* b1   = (const float*)d_in[2];
    const float* W2   = (const float*)d_in[3];
    const float* b2   = (const float*)d_in[4];
    const int* src = (const int*)d_in[5];
    const int* dst = (const int*)d_in[6];
    float* out = (float*)d_out;

    int N  = in_sizes[0] / 64;       // 50000
    int E  = in_sizes[5];            // 800000
    int NB = (N + 255) >> 8;         // 196 bins of 256 nodes
    int T  = (E + EPB - 1) / EPB;    // 391 hist/partition chunks
    int M  = NB * T;                 // per-side flat (bin, chunk) counts

    // workspace: bases/cursors | per-node | dhist | edge arrays | fp16 | f32
    int* wsi = (int*)d_ws;
    int* binBase     = wsi;                          // 2*(NB+1) (written by K2)
    int* cursor      = binBase + 2 * (NB + 1);       // 2*NB     (written by K2)
    int* in_deg      = cursor + 2 * NB;              // N
    int* row_start   = in_deg + N;                   // N
    int* out_deg     = row_start + N;                // N
    int* dhist       = out_deg + N;                  // 2*M (fully overwritten)
    int* packed      = dhist + 2 * M;                // E
    int* csr_src     = packed + E;                   // E
    unsigned char* srcPartB = (unsigned char*)(csr_src + E);      // E bytes
    size_t int_bytes = ((size_t)(4 * NB + 2) + 3 * (size_t)N + 2 * (size_t)M + 2 * (size_t)E) * sizeof(int)
                     + (size_t)E;
    size_t half_off  = (int_bytes + 15) & ~(size_t)15;
    __half* featp = (__half*)((char*)d_ws + half_off);            // 64N fp16
    float* s_buf  = (float*)((char*)d_ws + half_off + (size_t)64 * N * sizeof(__half));

    int* dstBinBase = binBase;
    int* srcBinBase = binBase + (NB + 1);
    int* dstCursor  = cursor;
    int* srcCursor  = cursor + NB;

    histA_featw1_kernel<<<T + (N + 63) / 64, BS, 0, stream>>>(
        src, dst, feat, W1, dhist, featp, E, N, NB, T, M);
    scan_bins_kernel<<<2, 1024, 0, stream>>>(dhist, binBase, cursor, NB, T, M);
    partition_kernel<<<T, BS, 0, stream>>>(
        src, dst, dhist, dstCursor, srcCursor, packed, srcPartB, E, NB, T, M);
    finalize_kernel<<<2 * NB, BS, 0, stream>>>(
        dstBinBase, srcBinBase, packed, srcPartB, csr_src, in_deg, row_start,
        out_deg, featp, N, NB);
    csr_agg1_kernel<<<(int)(((size_t)N * 64 + BS - 1) / BS), BS, 0, stream>>>(
        row_start, in_deg, csr_src, out_deg, featp, b1, W2, s_buf, N);
    csr_agg2_kernel<<<(int)(((size_t)N * 16 + BS - 1) / BS), BS, 0, stream>>>(
        row_start, in_deg, csr_src, s_buf, b2, out, N);
}

// Round 13
// 157.179 us; speedup vs baseline: 1.3797x; 1.1579x over previous
//
#include <hip/hip_runtime.h>
#include <hip/hip_fp16.h>
#include <math.h>

// GCN 2-layer (DGL GraphConv norm='both'). ROUND-6 CHAMPION VERBATIM (159.8us)
// -- re-landed after rounds 7-12 proved every alternative worse:
//   r7/r8 cooperative launch: harness pathology (650-850us, 20x rocprof)
//   r9 persistent + SW grid barrier: atomic spin serialization (1206us)
//   r10 scan grafted into K1: regalloc flip -> W1 spill (VGPR 56, 66us)
//   r11 2-block serial scan: latency trap (55us @ 0.08% occupancy)
//   r12 6-launch cursor-atomic consolidation: 182us (vs this structure's 159.8)
// Structure: two-level MSD counting sort on dst (CSR build) and src (out_deg),
// ZERO global atomics: per-block LDS hists -> flat [dhist|shist], hierarchical
// 3-kernel scan, single-pass partition from precomputed bases.
//   K1 histA_featw1 (regalloc-fragile -- byte-identical, do not touch):
//      LDS hists of dst>>8 / src>>8 -> dhist[bin*T+b | M+...]; featw1 =
//      fp16(feat @ W1) UNNORMALIZED, W1 column in 64 NAMED VGPRs, feat via LDS.
//   K2/K3/K4 scan1/scan2/scan3: hierarchical exclusive scan of dhist[2M]
//      (75 blocks); src section prefixes carry +E offset.
//   K5 partition: single pass, both scatters from precomputed (bin,chunk)
//      bases: packed = src|dstLow<<17 by dst bin; srcPartB byte by src bin.
//   K6 finalize (2*NB blocks): dst bins -> in_deg/row_start/csr_src scatter;
//      src bins -> out_deg + featp *= rsqrt(out_deg) pre-scale.
//   K7 agg1: one wave/node, 8 edge-groups x 8 fp16 chunks; featp pre-scaled;
//      relu+b1+.W2 epilogue -> s_buf (scalar per node).
//   K8 agg2: 16 lanes/node, sum s_buf[src] -> sigmoid -> out.
// Requires N <= 65536 (src packed into 17 bits, NB <= 256). N=50000 here.

#define BS 256
#define EPB 2048    // edges per hist/partition block (8 iters of 256)
#define SCB 2048    // elements per scan block (256 thr x 8)

// ---- A: per-block dst+src hists + featw1 ----
__global__ __launch_bounds__(256, 4)
void histA_featw1_kernel(const int* __restrict__ src, const int* __restrict__ dst,
                         const float* __restrict__ feat, const float* __restrict__ W1,
                         int* __restrict__ dhist,
                         __half* __restrict__ featp,
                         int E, int N, int NB, int T, int M) {
    __shared__ float4 ftile[64 * 16];   // 64 feat rows (16KB)
    __shared__ int histD[256];
    __shared__ int histS[256];
    int tid = threadIdx.x;
    if ((int)blockIdx.x < T) {
        histD[tid] = 0; histS[tid] = 0;
        __syncthreads();
        int base = blockIdx.x * EPB;
        #pragma unroll
        for (int it = 0; it < EPB / BS; it++) {
            int e = base + it * BS + tid;
            if (e < E) {
                atomicAdd(&histD[dst[e] >> 8], 1);
                atomicAdd(&histS[src[e] >> 8], 1);
            }
        }
        __syncthreads();
        if (tid < NB) {
            dhist[tid * T + (int)blockIdx.x] = histD[tid];
            dhist[M + tid * T + (int)blockIdx.x] = histS[tid];
        }
    } else {
        int lane = tid & 63;
        int wave = tid >> 6;
        // W1 column for this lane: 64 named scalars (static -> registers).
        #define WD(i) float wv##i = W1[(i) * 64 + lane];
        WD(0)  WD(1)  WD(2)  WD(3)  WD(4)  WD(5)  WD(6)  WD(7)
        WD(8)  WD(9)  WD(10) WD(11) WD(12) WD(13) WD(14) WD(15)
        WD(16) WD(17) WD(18) WD(19) WD(20) WD(21) WD(22) WD(23)
        WD(24) WD(25) WD(26) WD(27) WD(28) WD(29) WD(30) WD(31)
        WD(32) WD(33) WD(34) WD(35) WD(36) WD(37) WD(38) WD(39)
        WD(40) WD(41) WD(42) WD(43) WD(44) WD(45) WD(46) WD(47)
        WD(48) WD(49) WD(50) WD(51) WD(52) WD(53) WD(54) WD(55)
        WD(56) WD(57) WD(58) WD(59) WD(60) WD(61) WD(62) WD(63)
        #undef WD
        // stage 64 feat rows into LDS (coalesced, 4 float4/thread)
        int rBase = ((int)blockIdx.x - T) * 64;
        const float4* feat4 = (const float4*)feat;
        int maxF4 = N * 16 - 1;
        #pragma unroll
        for (int it = 0; it < 4; it++) {
            int idx = it * BS + tid;
            ftile[idx] = feat4[min(rBase * 16 + idx, maxF4)];
        }
        __syncthreads();
        // 16 rows per wave; per row: 16 b128 broadcast reads + 64 FMA
        #pragma unroll 1
        for (int rr = 0; rr < 16; rr++) {
            int r = wave * 16 + rr;
            const float4* ft = &ftile[r * 16];
            float a0 = 0.0f, a1 = 0.0f, a2 = 0.0f, a3 = 0.0f;
            #define RK(k4, wA, wB, wC, wD_) { float4 f = ft[k4]; \
                a0 = fmaf(f.x, wA, a0); a1 = fmaf(f.y, wB, a1); \
                a2 = fmaf(f.z, wC, a2); a3 = fmaf(f.w, wD_, a3); }
            RK(0,  wv0,  wv1,  wv2,  wv3)  RK(1,  wv4,  wv5,  wv6,  wv7)
            RK(2,  wv8,  wv9,  wv10, wv11) RK(3,  wv12, wv13, wv14, wv15)
            RK(4,  wv16, wv17, wv18, wv19) RK(5,  wv20, wv21, wv22, wv23)
            RK(6,  wv24, wv25, wv26, wv27) RK(7,  wv28, wv29, wv30, wv31)
            RK(8,  wv32, wv33, wv34, wv35) RK(9,  wv36, wv37, wv38, wv39)
            RK(10, wv40, wv41, wv42, wv43) RK(11, wv44, wv45, wv46, wv47)
            RK(12, wv48, wv49, wv50, wv51) RK(13, wv52, wv53, wv54, wv55)
            RK(14, wv56, wv57, wv58, wv59) RK(15, wv60, wv61, wv62, wv63)
            #undef RK
            int rowg = rBase + r;
            if (rowg < N)
                featp[(size_t)rowg * 64 + lane] = __float2half((a0 + a1) + (a2 + a3));
        }
    }
}

// ---- S1: per-block sums of dhist chunks ----
__global__ void scan1_kernel(const int* __restrict__ dhist, int* __restrict__ bsum, int M2) {
    __shared__ int s[256];
    int t = threadIdx.x;
    int base = blockIdx.x * SCB + t * 8;
    int sum = 0;
    #pragma unroll
    for (int i = 0; i < 8; i++) {
        int k = base + i;
        if (k < M2) sum += dhist[k];
    }
    s[t] = sum; __syncthreads();
    for (int off = 1; off < 256; off <<= 1) {
        int u = (t >= off) ? s[t - off] : 0; __syncthreads();
        s[t] += u; __syncthreads();
    }
    if (t == 255) bsum[blockIdx.x] = s[255];
}

// ---- S2: exclusive scan of block sums (NSB <= 256) ----
__global__ void scan2_kernel(int* __restrict__ bsum, int NSB) {
    __shared__ int s[256];
    int t = threadIdx.x;
    int v = (t < NSB) ? bsum[t] : 0;
    s[t] = v; __syncthreads();
    for (int off = 1; off < 256; off <<= 1) {
        int u = (t >= off) ? s[t - off] : 0; __syncthreads();
        s[t] += u; __syncthreads();
    }
    if (t < NSB) bsum[t] = s[t] - v;   // exclusive
}

// ---- S3: full exclusive scan of dhist in place ----
__global__ void scan3_kernel(int* __restrict__ dhist, const int* __restrict__ bsum, int M2) {
    __shared__ int s[256];
    int t = threadIdx.x;
    int base = blockIdx.x * SCB + t * 8;
    int v[8];
    int sum = 0;
    #pragma unroll
    for (int i = 0; i < 8; i++) {
        int k = base + i;
        v[i] = (k < M2) ? dhist[k] : 0;
        sum += v[i];
    }
    s[t] = sum; __syncthreads();
    for (int off = 1; off < 256; off <<= 1) {
        int u = (t >= off) ? s[t - off] : 0; __syncthreads();
        s[t] += u; __syncthreads();
    }
    int run = bsum[blockIdx.x] + s[t] - sum;   // exclusive prefix for this thread
    #pragma unroll
    for (int i = 0; i < 8; i++) {
        int k = base + i;
        if (k < M2) dhist[k] = run;
        run += v[i];
    }
}

// ---- B: single-pass partition: dst scatter (packed) + src scatter (bytes) ----
__global__ void partition_kernel(const int* __restrict__ src, const int* __restrict__ dst,
                                 const int* __restrict__ dhist,
                                 int* __restrict__ packed, unsigned char* __restrict__ srcPartB,
                                 int E, int NB, int T, int M) {
    __shared__ int darr[256];
    __shared__ int sarr[256];
    int tid = threadIdx.x;
    int b = blockIdx.x;
    darr[tid] = (tid < NB) ? dhist[tid * T + b] : 0;
    sarr[tid] = (tid < NB) ? (dhist[M + tid * T + b] - E) : 0;   // src section carries +E
    __syncthreads();
    int base = b * EPB;
    #pragma unroll
    for (int it = 0; it < EPB / BS; it++) {
        int e = base + it * BS + tid;
        if (e < E) {
            int d = dst[e], s2 = src[e];
            int pos = atomicAdd(&darr[d >> 8], 1);
            packed[pos] = s2 | ((d & 255) << 17);
            int pos2 = atomicAdd(&sarr[s2 >> 8], 1);
            srcPartB[pos2] = (unsigned char)(s2 & 255);
        }
    }
}

// ---- D: dst bins -> in_deg/row_start/csr_src; src bins -> out_deg + rescale ----
__global__ void finalize_kernel(const int* __restrict__ dhist,
                                const int* __restrict__ packed,
                                const unsigned char* __restrict__ srcPartB,
                                int* __restrict__ csr_src, int* __restrict__ in_deg,
                                int* __restrict__ row_start, int* __restrict__ out_deg,
                                __half* __restrict__ featp,
                                int N, int NB, int T, int M, int E) {
    __shared__ int hist[256];
    __shared__ int sc[256];
    int tid = threadIdx.x;
    int b = blockIdx.x;
    if (b < NB) {
        int lo = dhist[b * T];
        int hi = (b + 1 < NB) ? dhist[(b + 1) * T] : E;
        hist[tid] = 0; __syncthreads();
        for (int i = lo + tid; i < hi; i += BS)
            atomicAdd(&hist[(packed[i] >> 17) & 255], 1);
        __syncthreads();
        int v = hist[tid];
        sc[tid] = v; __syncthreads();
        for (int off = 1; off < 256; off <<= 1) {
            int u = (tid >= off) ? sc[tid - off] : 0; __syncthreads();
            sc[tid] += u; __syncthreads();
        }
        int ex = sc[tid] - v;          // exclusive within bin
        int n = b * 256 + tid;
        if (n < N) { in_deg[n] = v; row_start[n] = lo + ex; }
        sc[tid] = lo + ex;             // becomes the scatter cursor
        __syncthreads();
        for (int i = lo + tid; i < hi; i += BS) {
            int pv = packed[i];
            int pos = atomicAdd(&sc[(pv >> 17) & 255], 1);
            csr_src[pos] = pv & 0x1FFFF;
        }
    } else {
        int sb = b - NB;
        int lo = dhist[M + sb * T] - E;
        int hi = ((sb + 1 < NB) ? dhist[M + (sb + 1) * T] : 2 * E) - E;
        hist[tid] = 0; __syncthreads();
        for (int i = lo + tid; i < hi; i += BS)
            atomicAdd(&hist[srcPartB[i]], 1);
        __syncthreads();
        int n = sb * 256 + tid;
        int od = hist[tid];
        if (n < N) out_deg[n] = od;
        float* snorm = (float*)sc;     // reuse LDS
        snorm[tid] = rsqrtf(fmaxf((float)od, 1.0f));
        __syncthreads();
        // pre-scale featp rows of this bin by out_norm (contiguous 32KB block)
        int nodes = min(256, N - sb * 256);
        uint4* fp = (uint4*)(featp + (size_t)sb * 256 * 64);   // 8 uint4 per row
        int total = nodes * 8;
        for (int i = tid; i < total; i += BS) {
            float s = snorm[i >> 3];   // 8 lanes share a node -> LDS broadcast
            uint4 u = fp[i];
            __half2* hh = (__half2*)&u;
            #pragma unroll
            for (int c = 0; c < 4; c++) {
                float2 p = __half22float2(hh[c]);
                p.x *= s; p.y *= s;
                hh[c] = __float22half2_rn(p);
            }
            fp[i] = u;
        }
    }
}

// ---- agg1: one wave/node; 8 edge-groups x 8 chunks, unroll-2; featp pre-scaled ----
__global__ void csr_agg1_kernel(const int* __restrict__ row_start, const int* __restrict__ in_deg,
                                const int* __restrict__ csr_src, const int* __restrict__ out_deg,
                                const __half* __restrict__ featp,
                                const float* __restrict__ b1, const float* __restrict__ W2,
                                float* __restrict__ s_buf, int N) {
    int gid = blockIdx.x * blockDim.x + threadIdx.x;
    int n = gid >> 6;
    if (n >= N) return;
    int lane = threadIdx.x & 63;
    int g = lane >> 3;   // edge slot within batch of 8
    int l = lane & 7;    // feature chunk: features [8l, 8l+8)
    int start = row_start[n];
    int deg = in_deg[n];
    float acc[8] = {0, 0, 0, 0, 0, 0, 0, 0};
    const uint4* fp4 = (const uint4*)featp;
    for (int j = 0; j < deg; j += 16) {
        int e0 = j + g;
        int e1 = j + 8 + g;
        bool p0 = e0 < deg;
        bool p1 = e1 < deg;
        int sn0 = p0 ? csr_src[start + e0] : 0;
        int sn1 = p1 ? csr_src[start + e1] : 0;
        uint4 q0 = {0, 0, 0, 0}, q1 = {0, 0, 0, 0};
        if (p0) q0 = fp4[(size_t)sn0 * 8 + l];
        if (p1) q1 = fp4[(size_t)sn1 * 8 + l];
        const __half2* h0 = (const __half2*)&q0;
        const __half2* h1 = (const __half2*)&q1;
        #pragma unroll
        for (int c = 0; c < 4; c++) {
            float2 f0 = __half22float2(h0[c]);
            float2 f1 = __half22float2(h1[c]);
            acc[2 * c]     += f0.x + f1.x;
            acc[2 * c + 1] += f0.y + f1.y;
        }
    }
    #pragma unroll
    for (int off = 8; off < 64; off <<= 1) {
        #pragma unroll
        for (int c = 0; c < 8; c++)
            acc[c] += __shfl_xor(acc[c], off, 64);
    }
    float inn = rsqrtf(fmaxf((float)deg, 1.0f));
    float v = 0.0f;
    #pragma unroll
    for (int c = 0; c < 8; c++) {
        float h = fmaxf(inn * acc[c] + b1[l * 8 + c], 0.0f);
        v += h * W2[l * 8 + c];
    }
    #pragma unroll
    for (int off = 1; off < 8; off <<= 1)
        v += __shfl_xor(v, off, 64);
    if (lane == 0)
        s_buf[n] = rsqrtf(fmaxf((float)out_deg[n], 1.0f)) * v;
}

// ---- agg2: 16 lanes/node, unroll-2, sigmoid -> out ----
__global__ void csr_agg2_kernel(const int* __restrict__ row_start, const int* __restrict__ in_deg,
                                const int* __restrict__ csr_src,
                                const float* __restrict__ s_buf, const float* __restrict__ b2,
                                float* __restrict__ out, int N) {
    int gid = blockIdx.x * blockDim.x + threadIdx.x;
    int n = gid >> 4;
    if (n >= N) return;
    int sub = gid & 15;
    int start = row_start[n];
    int deg = in_deg[n];
    float a = 0.0f;
    for (int j = sub; j < deg; j += 32) {
        int j1 = j + 16;
        int i0 = csr_src[start + j];
        int i1 = (j1 < deg) ? csr_src[start + j1] : 0;
        float v0 = s_buf[i0];
        float v1 = (j1 < deg) ? s_buf[i1] : 0.0f;
        a += v0 + v1;
    }
    #pragma unroll
    for (int off = 1; off < 16; off <<= 1)
        a += __shfl_xor(a, off, 64);
    if (sub == 0) {
        float x = rsqrtf(fmaxf((float)deg, 1.0f)) * a + b2[0];
        out[n] = 1.0f / (1.0f + expf(-x));
    }
}

extern "C" void kernel_launch(void* const* d_in, const int* in_sizes, int n_in,
                              void* d_out, int out_size, void* d_ws, size_t ws_size,
                              hipStream_t stream) {
    const float* feat = (const float*)d_in[0];
    const float* W1   = (const float*)d_in[1];
    const float* b1   = (const float*)d_in[2];
    const float* W2   = (const float*)d_in[3];
    const float* b2   = (const float*)d_in[4];
    const int* src = (const int*)d_in[5];
    const int* dst = (const int*)d_in[6];
    float* out = (float*)d_out;

    const int N  = in_sizes[0] / 64;       // 50000
    const int E  = in_sizes[5];            // 800000
    const int NB = (N + 255) >> 8;         // 196 bins of 256 nodes
    const int T  = (E + EPB - 1) / EPB;    // 391 hist/partition blocks
    const int M  = NB * T;                 // per-side flat (bin, block) counts
    const int M2 = 2 * M;                  // [dhist | shist]
    const int NSB = (M2 + SCB - 1) / SCB;  // scan blocks (75)

    // workspace: int region | srcPart bytes | fp16 featp (16B-aligned) | float s_buf
    int* wsi = (int*)d_ws;
    int* bsum        = wsi;                          // NSB
    int* in_deg      = bsum + NSB;                   // N
    int* row_start   = in_deg + N;                   // N
    int* out_deg     = row_start + N;                // N (fully written by finalize)
    int* dhist       = out_deg + N;                  // 2*M (fully overwritten)
    int* packed      = dhist + M2;                   // E
    int* csr_src     = packed + E;                   // E
    unsigned char* srcPartB = (unsigned char*)(csr_src + E);      // E bytes
    size_t int_bytes = ((size_t)NSB + 3 * (size_t)N + (size_t)M2 + 2 * (size_t)E) * sizeof(int)
                     + (size_t)E;
    size_t half_off  = (int_bytes + 15) & ~(size_t)15;
    __half* featp = (__half*)((char*)d_ws + half_off);            // 64N fp16
    float* s_buf  = (float*)((char*)d_ws + half_off + (size_t)64 * N * sizeof(__half));

    histA_featw1_kernel<<<T + (N + 63) / 64, BS, 0, stream>>>(
        src, dst, feat, W1, dhist, featp, E, N, NB, T, M);
    scan1_kernel<<<NSB, 256, 0, stream>>>(dhist, bsum, M2);
    scan2_kernel<<<1, 256, 0, stream>>>(bsum, NSB);
    scan3_kernel<<<NSB, 256, 0, stream>>>(dhist, bsum, M2);
    partition_kernel<<<T, BS, 0, stream>>>(src, dst, dhist, packed, srcPartB, E, NB, T, M);
    finalize_kernel<<<2 * NB, BS, 0, stream>>>(
        dhist, packed, srcPartB, csr_src, in_deg, row_start, out_deg, featp, N, NB, T, M, E);
    csr_agg1_kernel<<<(int)(((size_t)N * 64 + BS - 1) / BS), BS, 0, stream>>>(
        row_start, in_deg, csr_src, out_deg, featp, b1, W2, s_buf, N);
    csr_agg2_kernel<<<(int)(((size_t)N * 16 + BS - 1) / BS), BS, 0, stream>>>(
        row_start, in_deg, csr_src, s_buf, b2, out, N);
}

// Round 14
// 155.275 us; speedup vs baseline: 1.3966x; 1.0123x over previous
//
#include <hip/hip_runtime.h>
#include <hip/hip_fp16.h>
#include <math.h>

// GCN 2-layer (DGL GraphConv norm='both'). SIX regular launches.
// Evolution of the r6/r13 champion (157.2us, 8 launches): the 3-kernel
// hierarchical flat scan is replaced by ONE fully-parallel rowscan kernel
// (392 waves, one per (side,bin) row of dhist) + redundant 196-element
// binBase scans recomputed in LDS by each partition/finalize block.
// This avoids BOTH r12 failure modes (2-block scan latency trap; global
// cursor-atomic contention) while cutting 2 launch boundaries (~10us each,
// calibrated r6-vs-r12-vs-r13). Other proven-pathological vehicles not used:
// coop launch (r7/r8), SW grid barrier (r9), grafting into K1 (r10 regalloc).
//   K1 histA_featw1 (r6 VERBATIM -- regalloc-fragile, do not touch):
//      LDS hists of dst>>8 / src>>8 -> dhist[bin*T+b | M+...]; featw1 =
//      fp16(feat @ W1) UNNORMALIZED, W1 column in 64 NAMED VGPRs.
//   K2 rowscan: wave r does in-place exclusive scan of dhist row r
//      (T=391 ints, coalesced, 7 shfl-scan chunks) + rowTotal[r].
//   K3 partition: block b: LDS scan of rowTotal -> binExcl; base(bin,b) =
//      binExcl[bin] + rowPref[bin][b]; single-pass dual scatter
//      (packed = src|dstLow<<17 by dst bin; srcPartB byte by src bin, 0-based).
//   K4 finalize (2*NB blocks): same redundant scan for lo/hi; dst bins ->
//      in_deg/row_start/csr_src; src bins -> out_deg + featp *= rsqrt(out_deg).
//   K5 agg1: one wave/node, 8 edge-groups x 8 fp16 chunks; featp pre-scaled;
//      relu+b1+.W2 epilogue -> s_buf.   K6 agg2: 16 lanes/node -> sigmoid.
// Requires N <= 65536 (src packed into 17 bits, NB <= 256). N=50000 here.

#define BS 256
#define EPB 2048    // edges per hist/partition block (8 iters of 256)

// ---- K1: per-block dst+src hists + featw1 (r6 verbatim) ----
__global__ __launch_bounds__(256, 4)
void histA_featw1_kernel(const int* __restrict__ src, const int* __restrict__ dst,
                         const float* __restrict__ feat, const float* __restrict__ W1,
                         int* __restrict__ dhist,
                         __half* __restrict__ featp,
                         int E, int N, int NB, int T, int M) {
    __shared__ float4 ftile[64 * 16];   // 64 feat rows (16KB)
    __shared__ int histD[256];
    __shared__ int histS[256];
    int tid = threadIdx.x;
    if ((int)blockIdx.x < T) {
        histD[tid] = 0; histS[tid] = 0;
        __syncthreads();
        int base = blockIdx.x * EPB;
        #pragma unroll
        for (int it = 0; it < EPB / BS; it++) {
            int e = base + it * BS + tid;
            if (e < E) {
                atomicAdd(&histD[dst[e] >> 8], 1);
                atomicAdd(&histS[src[e] >> 8], 1);
            }
        }
        __syncthreads();
        if (tid < NB) {
            dhist[tid * T + (int)blockIdx.x] = histD[tid];
            dhist[M + tid * T + (int)blockIdx.x] = histS[tid];
        }
    } else {
        int lane = tid & 63;
        int wave = tid >> 6;
        // W1 column for this lane: 64 named scalars (static -> registers).
        #define WD(i) float wv##i = W1[(i) * 64 + lane];
        WD(0)  WD(1)  WD(2)  WD(3)  WD(4)  WD(5)  WD(6)  WD(7)
        WD(8)  WD(9)  WD(10) WD(11) WD(12) WD(13) WD(14) WD(15)
        WD(16) WD(17) WD(18) WD(19) WD(20) WD(21) WD(22) WD(23)
        WD(24) WD(25) WD(26) WD(27) WD(28) WD(29) WD(30) WD(31)
        WD(32) WD(33) WD(34) WD(35) WD(36) WD(37) WD(38) WD(39)
        WD(40) WD(41) WD(42) WD(43) WD(44) WD(45) WD(46) WD(47)
        WD(48) WD(49) WD(50) WD(51) WD(52) WD(53) WD(54) WD(55)
        WD(56) WD(57) WD(58) WD(59) WD(60) WD(61) WD(62) WD(63)
        #undef WD
        // stage 64 feat rows into LDS (coalesced, 4 float4/thread)
        int rBase = ((int)blockIdx.x - T) * 64;
        const float4* feat4 = (const float4*)feat;
        int maxF4 = N * 16 - 1;
        #pragma unroll
        for (int it = 0; it < 4; it++) {
            int idx = it * BS + tid;
            ftile[idx] = feat4[min(rBase * 16 + idx, maxF4)];
        }
        __syncthreads();
        // 16 rows per wave; per row: 16 b128 broadcast reads + 64 FMA
        #pragma unroll 1
        for (int rr = 0; rr < 16; rr++) {
            int r = wave * 16 + rr;
            const float4* ft = &ftile[r * 16];
            float a0 = 0.0f, a1 = 0.0f, a2 = 0.0f, a3 = 0.0f;
            #define RK(k4, wA, wB, wC, wD_) { float4 f = ft[k4]; \
                a0 = fmaf(f.x, wA, a0); a1 = fmaf(f.y, wB, a1); \
                a2 = fmaf(f.z, wC, a2); a3 = fmaf(f.w, wD_, a3); }
            RK(0,  wv0,  wv1,  wv2,  wv3)  RK(1,  wv4,  wv5,  wv6,  wv7)
            RK(2,  wv8,  wv9,  wv10, wv11) RK(3,  wv12, wv13, wv14, wv15)
            RK(4,  wv16, wv17, wv18, wv19) RK(5,  wv20, wv21, wv22, wv23)
            RK(6,  wv24, wv25, wv26, wv27) RK(7,  wv28, wv29, wv30, wv31)
            RK(8,  wv32, wv33, wv34, wv35) RK(9,  wv36, wv37, wv38, wv39)
            RK(10, wv40, wv41, wv42, wv43) RK(11, wv44, wv45, wv46, wv47)
            RK(12, wv48, wv49, wv50, wv51) RK(13, wv52, wv53, wv54, wv55)
            RK(14, wv56, wv57, wv58, wv59) RK(15, wv60, wv61, wv62, wv63)
            #undef RK
            int rowg = rBase + r;
            if (rowg < N)
                featp[(size_t)rowg * 64 + lane] = __float2half((a0 + a1) + (a2 + a3));
        }
    }
}

// ---- K2: one wave per dhist row: in-place exclusive scan + rowTotal ----
__global__ void rowscan_kernel(int* __restrict__ dhist, int* __restrict__ rowTotal,
                               int T, int R) {
    int gw = (int)((blockIdx.x * blockDim.x + threadIdx.x) >> 6);
    int lane = threadIdx.x & 63;
    if (gw >= R) return;
    int* row = dhist + (size_t)gw * T;
    int carry = 0;
    int nch = (T + 63) >> 6;
    for (int c = 0; c < nch; c++) {
        int idx = c * 64 + lane;
        int v = (idx < T) ? row[idx] : 0;
        int inc = v;
        #pragma unroll
        for (int off = 1; off < 64; off <<= 1) {
            int u = __shfl_up(inc, off, 64);
            if (lane >= off) inc += u;
        }
        if (idx < T) row[idx] = inc - v + carry;   // exclusive within row
        carry += __shfl(inc, 63, 64);              // broadcast row-chunk total
    }
    if (lane == 0) rowTotal[gw] = carry;
}

// ---- K3: partition: redundant binBase scan + single-pass dual scatter ----
__global__ void partition_kernel(const int* __restrict__ src, const int* __restrict__ dst,
                                 const int* __restrict__ dhist, const int* __restrict__ rowTotal,
                                 int* __restrict__ packed, unsigned char* __restrict__ srcPartB,
                                 int E, int NB, int T, int M) {
    __shared__ int sd[256], ss[256];
    __shared__ int darr[256], sarr[256];
    int tid = threadIdx.x;
    int b = blockIdx.x;
    int vd = (tid < NB) ? rowTotal[tid] : 0;
    int vs = (tid < NB) ? rowTotal[NB + tid] : 0;
    sd[tid] = vd; ss[tid] = vs;
    __syncthreads();
    for (int off = 1; off < 256; off <<= 1) {
        int ud = (tid >= off) ? sd[tid - off] : 0;
        int us = (tid >= off) ? ss[tid - off] : 0;
        __syncthreads();
        sd[tid] += ud; ss[tid] += us;
        __syncthreads();
    }
    // base(bin,b) = binExcl[bin] + rowPref[bin][b]
    darr[tid] = (tid < NB) ? ((sd[tid] - vd) + dhist[tid * T + b]) : 0;
    sarr[tid] = (tid < NB) ? ((ss[tid] - vs) + dhist[M + tid * T + b]) : 0;
    __syncthreads();
    int base = b * EPB;
    #pragma unroll
    for (int it = 0; it < EPB / BS; it++) {
        int e = base + it * BS + tid;
        if (e < E) {
            int d = dst[e], s2 = src[e];
            int pos = atomicAdd(&darr[d >> 8], 1);
            packed[pos] = s2 | ((d & 255) << 17);
            int pos2 = atomicAdd(&sarr[s2 >> 8], 1);
            srcPartB[pos2] = (unsigned char)(s2 & 255);
        }
    }
}

// ---- K4: finalize: dst bins -> CSR; src bins -> out_deg + featp rescale ----
__global__ void finalize_kernel(const int* __restrict__ rowTotal,
                                const int* __restrict__ packed,
                                const unsigned char* __restrict__ srcPartB,
                                int* __restrict__ csr_src, int* __restrict__ in_deg,
                                int* __restrict__ row_start, int* __restrict__ out_deg,
                                __half* __restrict__ featp,
                                int N, int NB) {
    __shared__ int sd[256], ss[256], td_[256], ts_[256];
    __shared__ int hist[256];
    __shared__ int sc[256];
    int tid = threadIdx.x;
    int b = blockIdx.x;
    int vd = (tid < NB) ? rowTotal[tid] : 0;
    int vs = (tid < NB) ? rowTotal[NB + tid] : 0;
    sd[tid] = vd; ss[tid] = vs; td_[tid] = vd; ts_[tid] = vs;
    __syncthreads();
    for (int off = 1; off < 256; off <<= 1) {
        int ud = (tid >= off) ? sd[tid - off] : 0;
        int us = (tid >= off) ? ss[tid - off] : 0;
        __syncthreads();
        sd[tid] += ud; ss[tid] += us;
        __syncthreads();
    }
    if (b < NB) {
        int lo = sd[b] - td_[b];       // exclusive binBase
        int hi = sd[b];                // inclusive = next bin's base
        hist[tid] = 0; __syncthreads();
        for (int i = lo + tid; i < hi; i += BS)
            atomicAdd(&hist[(packed[i] >> 17) & 255], 1);
        __syncthreads();
        int v = hist[tid];
        sc[tid] = v; __syncthreads();
        for (int off = 1; off < 256; off <<= 1) {
            int u = (tid >= off) ? sc[tid - off] : 0; __syncthreads();
            sc[tid] += u; __syncthreads();
        }
        int ex = sc[tid] - v;          // exclusive within bin
        int n = b * 256 + tid;
        if (n < N) { in_deg[n] = v; row_start[n] = lo + ex; }
        sc[tid] = lo + ex;             // becomes the scatter cursor
        __syncthreads();
        for (int i = lo + tid; i < hi; i += BS) {
            int pv = packed[i];
            int pos = atomicAdd(&sc[(pv >> 17) & 255], 1);
            csr_src[pos] = pv & 0x1FFFF;
        }
    } else {
        int sb = b - NB;
        int lo = ss[sb] - ts_[sb];
        int hi = ss[sb];
        hist[tid] = 0; __syncthreads();
        for (int i = lo + tid; i < hi; i += BS)
            atomicAdd(&hist[srcPartB[i]], 1);
        __syncthreads();
        int n = sb * 256 + tid;
        int od = hist[tid];
        if (n < N) out_deg[n] = od;
        float* snorm = (float*)sc;     // reuse LDS
        snorm[tid] = rsqrtf(fmaxf((float)od, 1.0f));
        __syncthreads();
        // pre-scale featp rows of this bin by out_norm (contiguous 32KB block)
        int nodes = min(256, N - sb * 256);
        uint4* fp = (uint4*)(featp + (size_t)sb * 256 * 64);   // 8 uint4 per row
        int total = nodes * 8;
        for (int i = tid; i < total; i += BS) {
            float s = snorm[i >> 3];   // 8 lanes share a node -> LDS broadcast
            uint4 u = fp[i];
            __half2* hh = (__half2*)&u;
            #pragma unroll
            for (int c = 0; c < 4; c++) {
                float2 p = __half22float2(hh[c]);
                p.x *= s; p.y *= s;
                hh[c] = __float22half2_rn(p);
            }
            fp[i] = u;
        }
    }
}

// ---- K5: agg1: one wave/node; 8 edge-groups x 8 chunks; featp pre-scaled ----
__global__ void csr_agg1_kernel(const int* __restrict__ row_start, const int* __restrict__ in_deg,
                                const int* __restrict__ csr_src, const int* __restrict__ out_deg,
                                const __half* __restrict__ featp,
                                const float* __restrict__ b1, const float* __restrict__ W2,
                                float* __restrict__ s_buf, int N) {
    int gid = blockIdx.x * blockDim.x + threadIdx.x;
    int n = gid >> 6;
    if (n >= N) return;
    int lane = threadIdx.x & 63;
    int g = lane >> 3;   // edge slot within batch of 8
    int l = lane & 7;    // feature chunk: features [8l, 8l+8)
    int start = row_start[n];
    int deg = in_deg[n];
    float acc[8] = {0, 0, 0, 0, 0, 0, 0, 0};
    const uint4* fp4 = (const uint4*)featp;
    for (int j = 0; j < deg; j += 16) {
        int e0 = j + g;
        int e1 = j + 8 + g;
        bool p0 = e0 < deg;
        bool p1 = e1 < deg;
        int sn0 = p0 ? csr_src[start + e0] : 0;
        int sn1 = p1 ? csr_src[start + e1] : 0;
        uint4 q0 = {0, 0, 0, 0}, q1 = {0, 0, 0, 0};
        if (p0) q0 = fp4[(size_t)sn0 * 8 + l];
        if (p1) q1 = fp4[(size_t)sn1 * 8 + l];
        const __half2* h0 = (const __half2*)&q0;
        const __half2* h1 = (const __half2*)&q1;
        #pragma unroll
        for (int c = 0; c < 4; c++) {
            float2 f0 = __half22float2(h0[c]);
            float2 f1 = __half22float2(h1[c]);
            acc[2 * c]     += f0.x + f1.x;
            acc[2 * c + 1] += f0.y + f1.y;
        }
    }
    #pragma unroll
    for (int off = 8; off < 64; off <<= 1) {
        #pragma unroll
        for (int c = 0; c < 8; c++)
            acc[c] += __shfl_xor(acc[c], off, 64);
    }
    float inn = rsqrtf(fmaxf((float)deg, 1.0f));
    float v = 0.0f;
    #pragma unroll
    for (int c = 0; c < 8; c++) {
        float h = fmaxf(inn * acc[c] + b1[l * 8 + c], 0.0f);
        v += h * W2[l * 8 + c];
    }
    #pragma unroll
    for (int off = 1; off < 8; off <<= 1)
        v += __shfl_xor(v, off, 64);
    if (lane == 0)
        s_buf[n] = rsqrtf(fmaxf((float)out_deg[n], 1.0f)) * v;
}

// ---- K6: agg2: 16 lanes/node, unroll-2, sigmoid -> out ----
__global__ void csr_agg2_kernel(const int* __restrict__ row_start, const int* __restrict__ in_deg,
                                const int* __restrict__ csr_src,
                                const float* __restrict__ s_buf, const float* __restrict__ b2,
                                float* __restrict__ out, int N) {
    int gid = blockIdx.x * blockDim.x + threadIdx.x;
    int n = gid >> 4;
    if (n >= N) return;
    int sub = gid & 15;
    int start = row_start[n];
    int deg = in_deg[n];
    float a = 0.0f;
    for (int j = sub; j < deg; j += 32) {
        int j1 = j + 16;
        int i0 = csr_src[start + j];
        int i1 = (j1 < deg) ? csr_src[start + j1] : 0;
        float v0 = s_buf[i0];
        float v1 = (j1 < deg) ? s_buf[i1] : 0.0f;
        a += v0 + v1;
    }
    #pragma unroll
    for (int off = 1; off < 16; off <<= 1)
        a += __shfl_xor(a, off, 64);
    if (sub == 0) {
        float x = rsqrtf(fmaxf((float)deg, 1.0f)) * a + b2[0];
        out[n] = 1.0f / (1.0f + expf(-x));
    }
}

extern "C" void kernel_launch(void* const* d_in, const int* in_sizes, int n_in,
                              void* d_out, int out_size, void* d_ws, size_t ws_size,
                              hipStream_t stream) {
    const float* feat = (const float*)d_in[0];
    const float* W1   = (const float*)d_in[1];
    const float* b1   = (const float*)d_in[2];
    const float* W2   = (const float*)d_in[3];
    const float* b2   = (const float*)d_in[4];
    const int* src = (const int*)d_in[5];
    const int* dst = (const int*)d_in[6];
    float* out = (float*)d_out;

    const int N  = in_sizes[0] / 64;       // 50000
    const int E  = in_sizes[5];            // 800000
    const int NB = (N + 255) >> 8;         // 196 bins of 256 nodes
    const int T  = (E + EPB - 1) / EPB;    // 391 hist/partition blocks
    const int M  = NB * T;                 // per-side flat (bin, block) counts
    const int R  = 2 * NB;                 // dhist rows (dst bins then src bins)

    // workspace: rowTotal | per-node | dhist | edge arrays | fp16 | f32
    int* wsi = (int*)d_ws;
    int* rowTotal    = wsi;                          // 2*NB (written by rowscan)
    int* in_deg      = rowTotal + R;                 // N
    int* row_start   = in_deg + N;                   // N
    int* out_deg     = row_start + N;                // N (fully written by finalize)
    int* dhist       = out_deg + N;                  // 2*M (fully overwritten)
    int* packed      = dhist + 2 * M;                // E
    int* csr_src     = packed + E;                   // E
    unsigned char* srcPartB = (unsigned char*)(csr_src + E);      // E bytes
    size_t int_bytes = ((size_t)R + 3 * (size_t)N + 2 * (size_t)M + 2 * (size_t)E) * sizeof(int)
                     + (size_t)E;
    size_t half_off  = (int_bytes + 15) & ~(size_t)15;
    __half* featp = (__half*)((char*)d_ws + half_off);            // 64N fp16
    float* s_buf  = (float*)((char*)d_ws + half_off + (size_t)64 * N * sizeof(__half));

    histA_featw1_kernel<<<T + (N + 63) / 64, BS, 0, stream>>>(
        src, dst, feat, W1, dhist, featp, E, N, NB, T, M);
    rowscan_kernel<<<(R * 64 + BS - 1) / BS, BS, 0, stream>>>(dhist, rowTotal, T, R);
    partition_kernel<<<T, BS, 0, stream>>>(
        src, dst, dhist, rowTotal, packed, srcPartB, E, NB, T, M);
    finalize_kernel<<<2 * NB, BS, 0, stream>>>(
        rowTotal, packed, srcPartB, csr_src, in_deg, row_start, out_deg, featp, N, NB);
    csr_agg1_kernel<<<(int)(((size_t)N * 64 + BS - 1) / BS), BS, 0, stream>>>(
        row_start, in_deg, csr_src, out_deg, featp, b1, W2, s_buf, N);
    csr_agg2_kernel<<<(int)(((size_t)N * 16 + BS - 1) / BS), BS, 0, stream>>>(
        row_start, in_deg, csr_src, s_buf, b2, out, N);
}